// Round 6
// baseline (835.327 us; speedup 1.0000x reference)
//
#include <hip/hip_runtime.h>
#include <cstdint>
#include <cstddef>

#define BSZ    32
#define SEQL   2048
#define ENCD   512
#define DE     1024   // DEC + ENC
#define NHEADS 8
#define IHD    1024   // INTERM * HEADS

typedef unsigned short u16;
typedef __bf16 bf16x8 __attribute__((ext_vector_type(8)));
typedef float floatx4 __attribute__((ext_vector_type(4)));
typedef unsigned short u16x8 __attribute__((ext_vector_type(8)));

__device__ __forceinline__ u16 f2bf(float f) {
    unsigned int u = __float_as_uint(f);
    u = (u + 0x7FFFu + ((u >> 16) & 1u)) >> 16;   // RNE
    return (u16)u;
}
__device__ __forceinline__ float bf2f(u16 v) {
    return __uint_as_float(((unsigned int)v) << 16);
}
__device__ __forceinline__ float softplus_f(float x) {
    return fmaxf(x, 0.0f) + log1pf(__expf(-fabsf(x)));
}
__device__ __forceinline__ float tanh_fast(float x) {
    const float e = __expf(2.0f * x);
    return 1.0f - 2.0f / (e + 1.0f);
}

// ---------------------------------------------------------------------------
// bid<128: WvT[n][k] = bf16(Wv[k][n]) 64x64 LDS tile transpose
// bid==128: Wf -> bf16 (8192 elems + 8 pad zeros)
// ---------------------------------------------------------------------------
__global__ __launch_bounds__(256) void conv_w_kernel(const float* __restrict__ Wv,
                                                     const float* __restrict__ Wf,
                                                     u16* __restrict__ WvT,
                                                     u16* __restrict__ wfb) {
    __shared__ float tile[64 * 65];
    const int bid = blockIdx.x, tid = threadIdx.x;
    if (bid == 128) {
        for (int i = tid; i < 8200; i += 256)
            wfb[i] = (i < 8192) ? f2bf(Wf[i]) : (u16)0;
        return;
    }
    const int nt = bid & 15, kt = bid >> 4;
    for (int i = tid; i < 4096; i += 256) {
        const int kk = i >> 6, nn = i & 63;
        tile[kk * 65 + nn] = Wv[(size_t)(kt * 64 + kk) * IHD + nt * 64 + nn];
    }
    __syncthreads();
    for (int i = tid; i < 4096; i += 256) {
        const int nn = i >> 6, kk = i & 63;
        WvT[(size_t)(nt * 64 + nn) * 512 + kt * 64 + kk] = f2bf(tile[kk * 65 + nn]);
    }
}

// ---------------------------------------------------------------------------
// prep: grid (BSZ, 33). y<32: 32 query cols, 8-way k-split + LDS reduce.
//       y==32: beta = sp(dec@Wb+bb); kappa += sp(dec@Wk+bk)
// ---------------------------------------------------------------------------
__global__ __launch_bounds__(256) void prep_kernel(
    const float* __restrict__ dec, const float* __restrict__ kappa_in,
    const float* __restrict__ Wq, const float* __restrict__ bq,
    const float* __restrict__ Wb, const float* __restrict__ bb,
    const float* __restrict__ Wk, const float* __restrict__ bk,
    float* __restrict__ query_ws, float* __restrict__ beta_ws,
    float* __restrict__ kappa_out)
{
    __shared__ float s_dec[DE];
    __shared__ float s_red[256];
    const int b = blockIdx.x, y = blockIdx.y, tid = threadIdx.x;
    for (int i = tid; i < DE; i += 256) s_dec[i] = dec[b * DE + i];
    __syncthreads();

    if (y < 32) {
        const int cl = tid & 31, kg = tid >> 5;
        const int col = y * 32 + cl;
        float a = 0.f;
        const float* w = Wq + col;
        #pragma unroll 4
        for (int k = kg * 128; k < kg * 128 + 128; ++k)
            a = fmaf(s_dec[k], w[(size_t)k * IHD], a);
        s_red[tid] = a;
        __syncthreads();
        if (tid < 32) {
            float s = 0.f;
            #pragma unroll
            for (int i = 0; i < 8; ++i) s += s_red[i * 32 + tid];
            query_ws[(size_t)b * IHD + col] = s + bq[col];
        }
    } else {
        const int h = tid & 7, kg = tid >> 3;   // 32 k-groups of 32
        float ab = 0.f, ak = 0.f;
        for (int k = kg * 32; k < kg * 32 + 32; ++k) {
            const float d = s_dec[k];
            ab = fmaf(d, Wb[k * NHEADS + h], ab);
            ak = fmaf(d, Wk[k * NHEADS + h], ak);
        }
        s_red[tid] = ab;
        __syncthreads();
        for (int off = 128; off >= 8; off >>= 1) {
            if (tid < off) s_red[tid] += s_red[tid + off];
            __syncthreads();
        }
        const float abT = (tid < 8) ? s_red[tid] : 0.f;
        __syncthreads();
        s_red[tid] = ak;
        __syncthreads();
        for (int off = 128; off >= 8; off >>= 1) {
            if (tid < off) s_red[tid] += s_red[tid + off];
            __syncthreads();
        }
        if (tid < 8) {
            beta_ws[b * NHEADS + tid]   = softplus_f(bb[tid] + abT);
            kappa_out[b * NHEADS + tid] = kappa_in[b * NHEADS + tid]
                                        + softplus_f(bk[tid] + s_red[tid]);
        }
    }
}

// ---------------------------------------------------------------------------
// Main fused kernel, A-STATIONARY. 1024 blocks x 512 threads (8 waves).
// Block stages its 64x512 enc tile (fp32->bf16, chunk-swizzled) into LDS ONCE.
// Then loops 8 n-slices: stage-1 MFMA with B fragments loaded straight from
// global wvT into registers (L2-resident, compiler-pipelined, NO barriers in
// the K-loop) -> tanh -> tT LDS -> stage-2 MFMA (t@Wf, k split across wc) ->
// acc2 across slices. Final: cross-wave khalf reduce via LDS, score in-block.
// Wave grid: wr = w>>1 (m-tile 0..3), wc = w&1 (col-half, also stage-2 k-half).
// ---------------------------------------------------------------------------
#define BM 64

__global__ __launch_bounds__(512, 2) void gemm_score_kernel(
    const float* __restrict__ enc, const u16* __restrict__ wvT,
    const float* __restrict__ bv, const u16* __restrict__ wfb,
    const float* __restrict__ bf_g, const float* __restrict__ mask,
    const float* __restrict__ query_ws, const float* __restrict__ beta_ws,
    const float* __restrict__ kappa_out, float* __restrict__ score_out)
{
    __shared__ __align__(16) u16 Ab[64 * 512];      // 65536 B, swizzled chunks
    __shared__ __align__(16) __bf16 tT[64 * 136];   // 17408 B (+8 col pad)
    __shared__ float s_p[4][2][16][8];              //  4096 B

    const int tid  = threadIdx.x;
    const int m0   = blockIdx.x * BM;
    const int b    = blockIdx.x >> 5;               // 32 blocks per batch
    const int lane = tid & 63;
    const int w    = tid >> 6;                      // 0..7
    const int wr   = w >> 1;                        // m-tile 0..3
    const int wc   = w & 1;                         // col-half / k-half
    const int fr   = lane & 15, quad = lane >> 4;

    // ---- stage A once: fp32 global -> bf16 LDS, chunk-swizzled.
    // chunk = 8 u16 = 16 B; row = 64 chunks; phys chunk = swap low3 by row&7.
    #pragma unroll
    for (int r = 0; r < 8; ++r) {
        const int s  = r * 512 + tid;               // 0..4095
        const int m  = s >> 6;                      // row 0..63 (wave-uniform)
        const int lc = s & 63;                      // logical chunk
        const int pc = (lc & 56) | ((lc & 7) ^ (m & 7));
        const float* gp = enc + (size_t)(m0 + m) * 512 + lc * 8;
        const float4 f0 = *(const float4*)gp;
        const float4 f1 = *(const float4*)(gp + 4);
        u16x8 o;
        o[0] = f2bf(f0.x); o[1] = f2bf(f0.y); o[2] = f2bf(f0.z); o[3] = f2bf(f0.w);
        o[4] = f2bf(f1.x); o[5] = f2bf(f1.y); o[6] = f2bf(f1.z); o[7] = f2bf(f1.w);
        *(u16x8*)&Ab[m * 512 + pc * 8] = o;
    }
    __syncthreads();

    const int arow  = wr * 16 + fr;
    const int abase = arow * 512;

    floatx4 acc2 = {};

    for (int nn = 0; nn < 8; ++nn) {
        const int n0 = nn * 128;

        // per-slice epilogue operands (registers; global reads, L2-resident)
        float qv[4];
        #pragma unroll
        for (int nt = 0; nt < 4; ++nt) {
            const int col = n0 + wc * 64 + nt * 16 + fr;
            qv[nt] = query_ws[(size_t)b * IHD + col] + bv[col];
        }
        bf16x8 wfr[2];
        #pragma unroll
        for (int kk = 0; kk < 2; ++kk)
            #pragma unroll
            for (int j = 0; j < 8; ++j)
                wfr[kk][j] = *(const __bf16*)
                    &wfb[(n0 + (wc * 2 + kk) * 32 + quad * 8 + j) * 8 + fr];

        // ---- stage-1 K-loop: NO barriers. A from LDS, B from global regs.
        floatx4 acc[4] = {};
        const u16* bB = wvT + (size_t)(n0 + wc * 64) * 512;
        #pragma unroll 4
        for (int ks = 0; ks < 16; ++ks) {           // 16 k-steps of 32
            const int koff = ks * 32 + quad * 8;    // u16 offset in row
            const int lc   = ks * 4 + quad;
            const int pc   = (lc & 56) | ((lc & 7) ^ (arow & 7));
            const bf16x8 af = *(const bf16x8*)&Ab[abase + pc * 8];
            #pragma unroll
            for (int nt = 0; nt < 4; ++nt) {
                const bf16x8 bfr = *(const bf16x8*)
                    &bB[(size_t)(nt * 16 + fr) * 512 + koff];
                acc[nt] = __builtin_amdgcn_mfma_f32_16x16x32_bf16(
                    af, bfr, acc[nt], 0, 0, 0);
            }
        }

        // ---- epilogue A: t = tanh(value + query + bv) -> tT (bf16)
        #pragma unroll
        for (int nt = 0; nt < 4; ++nt) {
            const int col = wc * 64 + nt * 16 + fr;
            #pragma unroll
            for (int reg = 0; reg < 4; ++reg) {
                const int row = wr * 16 + quad * 4 + reg;
                tT[row * 136 + col] = (__bf16)tanh_fast(acc[nt][reg] + qv[nt]);
            }
        }
        __syncthreads();

        // ---- epilogue B: stage-2 MFMA, wave (wr,wc): rows wr*16.., k-half wc
        #pragma unroll
        for (int kk = 0; kk < 2; ++kk) {
            const bf16x8 ta = *(const bf16x8*)
                &tT[(wr * 16 + fr) * 136 + (wc * 2 + kk) * 32 + quad * 8];
            acc2 = __builtin_amdgcn_mfma_f32_16x16x32_bf16(ta, wfr[kk], acc2, 0, 0, 0);
        }
        __syncthreads();   // protect tT before next slice's epilogue writes
    }

    // ---- cross-wave k-half reduce + score
    if (fr < NHEADS) {
        #pragma unroll
        for (int reg = 0; reg < 4; ++reg)
            s_p[wr][wc][quad * 4 + reg][fr] = acc2[reg];
    }
    __syncthreads();

    {
        const int row = tid >> 3;                   // 0..63
        const int h   = tid & 7;
        const float p = s_p[row >> 4][0][row & 15][h]
                      + s_p[row >> 4][1][row & 15][h];
        const int grow = m0 + row;
        const int s = grow & 2047;
        const float alpha = softplus_f(p + bf_g[h]) * mask[grow];
        const float bet = beta_ws[b * NHEADS + h];
        const float kap = kappa_out[b * NHEADS + h];
        const float du  = kap - (float)s;
        score_out[(size_t)grow * NHEADS + h] = alpha * __expf(-bet * du * du);
    }
}

// ---------------------------------------------------------------------------
// context partials: part[sc][b][h][e] = sum_{s in chunk} score[b,s,h]*enc[b,s,e]
// grid (b=32, sc=16). Wave w owns heads {2w,2w+1} x all 512 e. fp32 enc.
// ---------------------------------------------------------------------------
__global__ __launch_bounds__(256) void context_kernel(
    const float* __restrict__ enc, const float* __restrict__ score,
    float* __restrict__ ctx_part)
{
    __shared__ float s_sc[128 * NHEADS];
    const int b = blockIdx.x, sc = blockIdx.y, tid = threadIdx.x;
    const int lane = tid & 63, w = tid >> 6;
    const int e8 = lane * 8;
    const size_t srow0 = (size_t)b * SEQL + sc * 128;

    for (int i = tid; i < 128 * NHEADS; i += 256)
        s_sc[i] = score[srow0 * NHEADS + i];
    __syncthreads();

    float acc0[8] = {}, acc1[8] = {};
    const float* ep = enc + srow0 * ENCD + e8;
    #pragma unroll 4
    for (int s = 0; s < 128; ++s) {
        const float4 e0 = *(const float4*)(ep + (size_t)s * ENCD);
        const float4 e1 = *(const float4*)(ep + (size_t)s * ENCD + 4);
        const float ef[8] = {e0.x, e0.y, e0.z, e0.w, e1.x, e1.y, e1.z, e1.w};
        const float2 sc2 = *(const float2*)&s_sc[s * NHEADS + 2 * w];
        #pragma unroll
        for (int j = 0; j < 8; ++j) {
            acc0[j] = fmaf(sc2.x, ef[j], acc0[j]);
            acc1[j] = fmaf(sc2.y, ef[j], acc1[j]);
        }
    }

    float* outp = ctx_part + ((size_t)sc * BSZ + b) * (NHEADS * ENCD);
    *(float4*)&outp[(2 * w + 0) * ENCD + e8]     = make_float4(acc0[0], acc0[1], acc0[2], acc0[3]);
    *(float4*)&outp[(2 * w + 0) * ENCD + e8 + 4] = make_float4(acc0[4], acc0[5], acc0[6], acc0[7]);
    *(float4*)&outp[(2 * w + 1) * ENCD + e8]     = make_float4(acc1[0], acc1[1], acc1[2], acc1[3]);
    *(float4*)&outp[(2 * w + 1) * ENCD + e8 + 4] = make_float4(acc1[4], acc1[5], acc1[6], acc1[7]);
}

// ---------------------------------------------------------------------------
// ctx_ws[i] = sum_sc part[sc][i]   (i < 131072)
// ---------------------------------------------------------------------------
__global__ __launch_bounds__(256) void ctx_reduce_kernel(
    const float* __restrict__ part, float* __restrict__ ctx_ws)
{
    const int i = blockIdx.x * 256 + threadIdx.x;
    float a = 0.f;
    #pragma unroll
    for (int sc = 0; sc < 16; ++sc)
        a += part[(size_t)sc * 131072 + i];
    ctx_ws[i] = a;
}

// ---------------------------------------------------------------------------
// out_ctx[b,j] = ctx[b,:] @ Wfc[:,j] + bfc[j]
// ---------------------------------------------------------------------------
__global__ __launch_bounds__(256) void final_kernel(
    const float* __restrict__ ctx_ws, const float* __restrict__ Wfc,
    const float* __restrict__ bfc, float* __restrict__ out_ctx)
{
    __shared__ float s_ctx[32][128];
    const int jc = blockIdx.x, ks = blockIdx.y, tid = threadIdx.x;
    const int jl = tid & 31, bg = tid >> 5;
    const int j = jc * 32 + jl;
    float a0 = 0.f, a1 = 0.f, a2 = 0.f, a3 = 0.f;

    for (int t = 0; t < 4; ++t) {
        const int k0 = ks * 512 + t * 128;
        __syncthreads();
        for (int i = tid; i < 32 * 128; i += 256) {
            const int bb2 = i >> 7, kk = i & 127;
            s_ctx[bb2][kk] = ctx_ws[(size_t)bb2 * (NHEADS * ENCD) + k0 + kk];
        }
        __syncthreads();
        for (int kk = 0; kk < 128; ++kk) {
            const float wv = Wfc[(size_t)(k0 + kk) * ENCD + j];
            a0 = fmaf(s_ctx[bg * 4 + 0][kk], wv, a0);
            a1 = fmaf(s_ctx[bg * 4 + 1][kk], wv, a1);
            a2 = fmaf(s_ctx[bg * 4 + 2][kk], wv, a2);
            a3 = fmaf(s_ctx[bg * 4 + 3][kk], wv, a3);
        }
    }
    const float bias = (ks == 0) ? bfc[j] : 0.0f;
    atomicAdd(&out_ctx[(bg * 4 + 0) * ENCD + j], a0 + bias);
    atomicAdd(&out_ctx[(bg * 4 + 1) * ENCD + j], a1 + bias);
    atomicAdd(&out_ctx[(bg * 4 + 2) * ENCD + j], a2 + bias);
    atomicAdd(&out_ctx[(bg * 4 + 3) * ENCD + j], a3 + bias);
}

// ---------------------------------------------------------------------------
extern "C" void kernel_launch(void* const* d_in, const int* in_sizes, int n_in,
                              void* d_out, int out_size, void* d_ws, size_t ws_size,
                              hipStream_t stream)
{
    const float* enc   = (const float*)d_in[0];
    const float* dec   = (const float*)d_in[1];
    const float* kapin = (const float*)d_in[2];
    const float* mask  = (const float*)d_in[3];
    const float* Wv    = (const float*)d_in[4];
    const float* bv    = (const float*)d_in[5];
    const float* Wq    = (const float*)d_in[6];
    const float* bq    = (const float*)d_in[7];
    const float* Wf    = (const float*)d_in[8];
    const float* bf    = (const float*)d_in[9];
    const float* Wb    = (const float*)d_in[10];
    const float* bb    = (const float*)d_in[11];
    const float* Wk    = (const float*)d_in[12];
    const float* bk    = (const float*)d_in[13];
    const float* Wfc   = (const float*)d_in[14];
    const float* bfc   = (const float*)d_in[15];

    // outputs: context(32*512) | kappa(32*8) | score(32*2048*8)
    float* out       = (float*)d_out;
    float* out_ctx   = out;
    float* out_kappa = out + 16384;
    float* out_score = out + 16640;

    // workspace layout (bytes)
    char* w = (char*)d_ws;
    u16*   wvT      = (u16*)w;                     //  1048576 B
    u16*   wfb      = (u16*)(w + 1048576);         //    16400 B (+pad to 1065088)
    float* q_ws     = (float*)(w + 1065088);       //   131072 B
    float* beta_ws  = (float*)(w + 1196160);       //     1024 B
    float* ctx_ws   = (float*)(w + 1197184);       //   524288 B
    float* ctx_part = (float*)(w + 1721472);       //  8388608 B
                                                   // total 10110080 B

    hipMemsetAsync(out_ctx, 0, 16384 * sizeof(float), stream);

    conv_w_kernel<<<dim3(129), dim3(256), 0, stream>>>(Wv, Wf, wvT, wfb);

    prep_kernel<<<dim3(BSZ, 33), dim3(256), 0, stream>>>(
        dec, kapin, Wq, bq, Wb, bb, Wk, bk, q_ws, beta_ws, out_kappa);

    gemm_score_kernel<<<dim3((BSZ * SEQL) / BM), dim3(512), 0, stream>>>(
        enc, wvT, bv, wfb, bf, mask, q_ws, beta_ws, out_kappa, out_score);

    context_kernel<<<dim3(BSZ, 16), dim3(256), 0, stream>>>(
        enc, out_score, ctx_part);

    ctx_reduce_kernel<<<dim3(512), dim3(256), 0, stream>>>(ctx_part, ctx_ws);

    final_kernel<<<dim3(16, 8), dim3(256), 0, stream>>>(
        ctx_ws, Wfc, bfc, out_ctx);
}